// Round 3
// baseline (373.413 us; speedup 1.0000x reference)
//
#include <hip/hip_runtime.h>
#include <hip/hip_bf16.h>

#define N_NODES 100000
#define N_EDGES 1600000
#define NUM_GRAPHS 1000

#define NODES_PER_BUCKET 256
#define BUCKET_SHIFT 8
#define NBUCKETS 391              // ceil(100000/256)
#define CAP 5120                  // bucket capacity: mean 4096 + 16 sigma (deterministic input)

#define G1_BLOCKS 782             // ceil(100000/128)
#define BIN_BLOCKS 196            // 196*8192 >= 1.6M
#define FILL_CHUNK 8192
#define FUSED_BLOCKS (BIN_BLOCKS + G1_BLOCKS)   // bin first, then gemm

#define DEG_BLOCKS 200            // 200*8000 = 1.6M
#define DEG_CHUNK 8000

typedef __attribute__((ext_vector_type(8))) short short8;
typedef __attribute__((ext_vector_type(4))) float f32x4;
typedef __attribute__((ext_vector_type(2))) float f32x2;
typedef unsigned short ushort;

__device__ __forceinline__ ushort f2bf(float f) {
    unsigned int u = __float_as_uint(f);
    u = u + 0x7fffu + ((u >> 16) & 1u);      // round-to-nearest-even
    return (ushort)(u >> 16);
}

// fp8 e4m3 (OCP on gfx950) encode via HW converter
__device__ __forceinline__ unsigned char f2fp8(float f) {
    return (unsigned char)(__builtin_amdgcn_cvt_pk_fp8_f32(f, f, 0, false) & 0xff);
}

// ---------------- setup: bcursor, W1^T/W2^T bf16, zero gsum/gcnt, in-degree count ----------------
__global__ void setup_kernel(int* __restrict__ bcursor,
                             const float* __restrict__ W1, ushort* __restrict__ W1t,
                             const float* __restrict__ W2, ushort* __restrict__ W2t,
                             float* __restrict__ gsum, float* __restrict__ gcnt,
                             const int* __restrict__ edst, int* __restrict__ deg) {
    int b = blockIdx.x, tid = threadIdx.x;
    if (b < 2) {
        int i = b * 256 + tid;
        if (i < NBUCKETS) bcursor[i] = i * CAP;
    } else if (b < 130) {
        int idx = (b - 2) * 256 + tid;               // 32768
        int n = idx & 127, k = idx >> 7;
        W1t[n * 256 + k] = f2bf(W1[k * 128 + n]);
    } else if (b < 162) {
        int idx = (b - 130) * 256 + tid;             // 8192
        int n = idx & 63, k = idx >> 6;
        W2t[n * 128 + k] = f2bf(W2[k * 64 + n]);
    } else if (b < 416) {
        int idx = (b - 162) * 256 + tid;
        if (idx < NUM_GRAPHS * 64) gsum[idx] = 0.f;
        else if (idx < NUM_GRAPHS * 64 + NUM_GRAPHS) gcnt[idx - NUM_GRAPHS * 64] = 0.f;
    } else {
        // deg role: in-degree histogram (deg zeroed via hipMemsetAsync before launch)
        const int fid = b - 416;
        const int beg = fid * DEG_CHUNK;
        int end = beg + DEG_CHUNK;
        if (end > N_EDGES) end = N_EDGES;
        for (int e = beg + tid * 4; e < end; e += 1024) {
            int4 d4 = *(const int4*)&edst[e];
            atomicAdd(&deg[d4.x], 1);
            atomicAdd(&deg[d4.y], 1);
            atomicAdd(&deg[d4.z], 1);
            atomicAdd(&deg[d4.w], 1);
        }
    }
}
#define SETUP_BLOCKS (416 + DEG_BLOCKS)

// ---------------- fused: GEMM1 (LDS-broadcast B, dinv-scaled fp8 out) + edge binning ----------------
__global__ __launch_bounds__(256) void gemm1_fill_kernel(const float* __restrict__ x,
                                                         const ushort* __restrict__ W1t,
                                                         const int* __restrict__ deg,
                                                         unsigned char* __restrict__ outb,
                                                         const int* __restrict__ esrc,
                                                         const int* __restrict__ edst,
                                                         int* __restrict__ bcursor,
                                                         int* __restrict__ pairs) {
    // 32 KB: B fragments for half the K range, layout [kcl(4)][t(8)][lrow(16)][quad(4)] x 16B
    __shared__ short8 Bs[2048];
    const int b = blockIdx.x;
    const int tid = threadIdx.x;

    if (b < BIN_BLOCKS) {
        // ---- bin role: pack (src<<8 | dst&255) into fixed-capacity dst-buckets ----
        int* scnt = (int*)Bs;
        int* spos = scnt + NBUCKETS;
        const int beg = b * FILL_CHUNK;
        int end = beg + FILL_CHUNK;
        if (end > N_EDGES) end = N_EDGES;
        if (beg >= end) return;
        for (int i = tid; i < NBUCKETS; i += 256) scnt[i] = 0;
        __syncthreads();
        for (int e = beg + tid * 4; e < end; e += 1024) {
            int4 d4 = *(const int4*)&edst[e];
            atomicAdd(&scnt[d4.x >> BUCKET_SHIFT], 1);
            atomicAdd(&scnt[d4.y >> BUCKET_SHIFT], 1);
            atomicAdd(&scnt[d4.z >> BUCKET_SHIFT], 1);
            atomicAdd(&scnt[d4.w >> BUCKET_SHIFT], 1);
        }
        __syncthreads();
        for (int i = tid; i < NBUCKETS; i += 256) {
            int c = scnt[i];
            spos[i] = c > 0 ? atomicAdd(&bcursor[i], c) : 0;
        }
        __syncthreads();
        for (int e = beg + tid * 4; e < end; e += 1024) {
            int4 d4 = *(const int4*)&edst[e];
            int4 s4 = *(const int4*)&esrc[e];
            int p0 = atomicAdd(&spos[d4.x >> BUCKET_SHIFT], 1);
            pairs[p0] = (s4.x << 8) | (d4.x & 255);
            int p1 = atomicAdd(&spos[d4.y >> BUCKET_SHIFT], 1);
            pairs[p1] = (s4.y << 8) | (d4.y & 255);
            int p2 = atomicAdd(&spos[d4.z >> BUCKET_SHIFT], 1);
            pairs[p2] = (s4.z << 8) | (d4.z & 255);
            int p3 = atomicAdd(&spos[d4.w >> BUCKET_SHIFT], 1);
            pairs[p3] = (s4.w << 8) | (d4.w & 255);
        }
        return;
    }

    // ---- GEMM role: 128 rows/block; A direct from global, B broadcast via LDS ----
    const int gid = b - BIN_BLOCKS;          // 0..781
    const int row0 = gid * 128;
    const int wv = tid >> 6;
    const int l = tid & 63;
    const int lrow = l & 15;
    const int quad = l >> 4;

    int r0 = row0 + wv * 16 + lrow;          // m=0 rows
    int r1 = r0 + 64;                        // m=1 rows
    if (r0 > N_NODES - 1) r0 = N_NODES - 1;
    if (r1 > N_NODES - 1) r1 = N_NODES - 1;
    const float* xr0 = x + (size_t)r0 * 256 + quad * 8;
    const float* xr1 = x + (size_t)r1 * 256 + quad * 8;
    const int frag = lrow * 4 + quad;        // fragment slot within a (kc,t) tile

    f32x4 acc[2][8];
#pragma unroll
    for (int m = 0; m < 2; ++m)
#pragma unroll
        for (int t = 0; t < 8; ++t) acc[m][t] = (f32x4){0.f, 0.f, 0.f, 0.f};

    for (int s = 0; s < 2; ++s) {
        if (s) __syncthreads();              // all waves done reading stage 0
        // stage 32 KB of W1t into fragment-ordered LDS: 8 x 16B per thread
#pragma unroll
        for (int j = 0; j < 8; ++j) {
            int slot = j * 256 + tid;
            int kcl = slot >> 9, t = (slot >> 6) & 7, lr = (slot >> 2) & 15, q = slot & 3;
            Bs[slot] = *(const short8*)(W1t + (t * 16 + lr) * 256 + (s * 4 + kcl) * 32 + q * 8);
        }
        __syncthreads();

#pragma unroll
        for (int kcl = 0; kcl < 4; ++kcl) {
            const int kc = s * 4 + kcl;
            float4 a00 = *(const float4*)(xr0 + kc * 32);
            float4 a01 = *(const float4*)(xr0 + kc * 32 + 4);
            float4 a10 = *(const float4*)(xr1 + kc * 32);
            float4 a11 = *(const float4*)(xr1 + kc * 32 + 4);
            short8 af0, af1;
            af0[0] = (short)f2bf(a00.x); af0[1] = (short)f2bf(a00.y);
            af0[2] = (short)f2bf(a00.z); af0[3] = (short)f2bf(a00.w);
            af0[4] = (short)f2bf(a01.x); af0[5] = (short)f2bf(a01.y);
            af0[6] = (short)f2bf(a01.z); af0[7] = (short)f2bf(a01.w);
            af1[0] = (short)f2bf(a10.x); af1[1] = (short)f2bf(a10.y);
            af1[2] = (short)f2bf(a10.z); af1[3] = (short)f2bf(a10.w);
            af1[4] = (short)f2bf(a11.x); af1[5] = (short)f2bf(a11.y);
            af1[6] = (short)f2bf(a11.z); af1[7] = (short)f2bf(a11.w);
#pragma unroll
            for (int t = 0; t < 8; ++t) {
                short8 bfrag = Bs[kcl * 512 + t * 64 + frag];
                acc[0][t] = __builtin_amdgcn_mfma_f32_16x16x32_bf16(af0, bfrag, acc[0][t], 0, 0, 0);
                acc[1][t] = __builtin_amdgcn_mfma_f32_16x16x32_bf16(af1, bfrag, acc[1][t], 0, 0, 0);
            }
        }
    }

    // epilogue: scale by dinv[row] = rsqrt(deg+1) BEFORE fp8 encode (single quantization)
    float sc[2][4];
#pragma unroll
    for (int m = 0; m < 2; ++m) {
        const int rb = row0 + m * 64 + wv * 16 + quad * 4;
#pragma unroll
        for (int r = 0; r < 4; ++r) {
            int row = rb + r;
            int dg = (row < N_NODES) ? deg[row] : 0;
            sc[m][r] = rsqrtf((float)(dg + 1));
        }
    }
#pragma unroll
    for (int m = 0; m < 2; ++m) {
        const int rbase = row0 + m * 64 + wv * 16 + quad * 4;
#pragma unroll
        for (int t = 0; t < 8; ++t) {
#pragma unroll
            for (int r = 0; r < 4; ++r) {
                int row = rbase + r;
                if (row < N_NODES)
                    outb[(size_t)row * 128 + t * 16 + lrow] = f2fp8(sc[m][r] * acc[m][t][r]);
            }
        }
    }
}

// ---------------- per-bucket CSR build: histogram + scan + scatter + row ranges ----------------
__global__ __launch_bounds__(256) void csr_fill_local_kernel(const int* __restrict__ pairs,
                                                             const int* __restrict__ bcursor,
                                                             int* __restrict__ csr_src,
                                                             int* __restrict__ row_beg,
                                                             int* __restrict__ row_end) {
    __shared__ int plds[CAP];        // 20 KB
    __shared__ int hist[256];
    __shared__ int scanv[256];
    __shared__ int cur[256];
    const int b = blockIdx.x;
    const int base = b * CAP;
    const int tid = threadIdx.x;
    const int cnt_b = bcursor[b] - base;

    for (int i = tid; i < cnt_b; i += 256) plds[i] = pairs[base + i];
    hist[tid] = 0;
    __syncthreads();
    for (int i = tid; i < cnt_b; i += 256) atomicAdd(&hist[plds[i] & 255], 1);
    __syncthreads();

    int deg = hist[tid];
    scanv[tid] = deg;
    for (int off = 1; off < 256; off <<= 1) {
        __syncthreads();
        int add = (tid >= off) ? scanv[tid - off] : 0;
        __syncthreads();
        scanv[tid] += add;
    }
    __syncthreads();
    int excl = scanv[tid] - deg;

    int node = b * NODES_PER_BUCKET + tid;
    if (node < N_NODES) {
        int beg = base + excl;
        row_beg[node] = beg;
        row_end[node] = beg + deg;
    }
    cur[tid] = excl;
    __syncthreads();

    for (int i = tid; i < cnt_b; i += 256) {
        int pr = plds[i];
        int pos = base + atomicAdd(&cur[pr & 255], 1);
        csr_src[pos] = ((unsigned int)pr) >> 8;
    }
}

// ---------------- agg1: h(bf16) = relu(dvn*(xs_v + sum xs_s) + b1); F=128 pre-scaled fp8 in ----------------
__global__ __launch_bounds__(256) void agg1_kernel(const unsigned int* __restrict__ xw,  // [N][32] fp8x4
                                                   const int* __restrict__ csr_src,
                                                   const int* __restrict__ row_beg,
                                                   const int* __restrict__ row_end,
                                                   const float* __restrict__ bias,
                                                   ushort* __restrict__ h) {      // bf16 [N][128]
    const int wave = threadIdx.x >> 6;
    const int lane = threadIdx.x & 63;
    const int h2 = lane >> 5;
    const int c = lane & 31;
    const int node = blockIdx.x * 8 + wave * 2 + h2;

    const int beg = row_beg[node], end = row_end[node];
    const float dvn = rsqrtf((float)(end - beg + 1));

    unsigned int sv = xw[(size_t)node * 32 + c];
    f32x2 slo = __builtin_amdgcn_cvt_pk_f32_fp8(sv, false);
    f32x2 shi = __builtin_amdgcn_cvt_pk_f32_fp8(sv, true);
    float a0 = slo[0], a1 = slo[1], a2 = shi[0], a3 = shi[1];

    for (int e = beg; e < end; e += 16) {
        int s[16];
        s[0] = csr_src[e];
#pragma unroll
        for (int i = 1; i < 16; ++i)
            s[i] = (e + i < end) ? csr_src[e + i] : s[0];
        unsigned int v[16];
#pragma unroll
        for (int i = 0; i < 16; ++i)
            v[i] = xw[(size_t)s[i] * 32 + c];
#pragma unroll
        for (int i = 0; i < 16; ++i) {
            if (i == 0 || e + i < end) {
                f32x2 lo = __builtin_amdgcn_cvt_pk_f32_fp8(v[i], false);
                f32x2 hi = __builtin_amdgcn_cvt_pk_f32_fp8(v[i], true);
                a0 += lo[0]; a1 += lo[1];
                a2 += hi[0]; a3 += hi[1];
            }
        }
    }
    float4 bv = *(const float4*)&bias[c * 4];
    float v0 = a0 * dvn + bv.x, v1 = a1 * dvn + bv.y;
    float v2 = a2 * dvn + bv.z, v3 = a3 * dvn + bv.w;
    ushort4 o;
    o.x = f2bf(v0 > 0.f ? v0 : 0.f);
    o.y = f2bf(v1 > 0.f ? v1 : 0.f);
    o.z = f2bf(v2 > 0.f ? v2 : 0.f);
    o.w = f2bf(v3 > 0.f ? v3 : 0.f);
    *(ushort4*)&h[(size_t)node * 128 + c * 4] = o;
}

// ---------------- GEMM2 (LDS-broadcast B, dinv-scaled fp8 out): outb = fp8(dinv*(h @ W2)) ----------------
__global__ __launch_bounds__(256) void gemm2_kernel(const ushort* __restrict__ h,
                                                    const ushort* __restrict__ W2t,
                                                    const int* __restrict__ deg,
                                                    unsigned char* __restrict__ outb) {
    // 16 KB: full W2t in fragment order [kc(4)][t(4)][lrow(16)][quad(4)] x 16B
    __shared__ short8 Bs[1024];
    const int tid = threadIdx.x;
    const int row0 = blockIdx.x * 128;
    const int wv = tid >> 6;
    const int l = tid & 63;
    const int lrow = l & 15;
    const int quad = l >> 4;

    int r0 = row0 + wv * 16 + lrow;
    int r1 = r0 + 64;
    if (r0 > N_NODES - 1) r0 = N_NODES - 1;
    if (r1 > N_NODES - 1) r1 = N_NODES - 1;
    const ushort* h0 = h + (size_t)r0 * 128 + quad * 8;
    const ushort* h1 = h + (size_t)r1 * 128 + quad * 8;
    const int frag = lrow * 4 + quad;

#pragma unroll
    for (int j = 0; j < 4; ++j) {
        int slot = j * 256 + tid;
        int kc = slot >> 8, t = (slot >> 6) & 3, lr = (slot >> 2) & 15, q = slot & 3;
        Bs[slot] = *(const short8*)(W2t + (t * 16 + lr) * 128 + kc * 32 + q * 8);
    }
    __syncthreads();

    f32x4 acc[2][4];
#pragma unroll
    for (int m = 0; m < 2; ++m)
#pragma unroll
        for (int t = 0; t < 4; ++t) acc[m][t] = (f32x4){0.f, 0.f, 0.f, 0.f};

#pragma unroll
    for (int kc = 0; kc < 4; ++kc) {
        short8 af0 = *(const short8*)(h0 + kc * 32);
        short8 af1 = *(const short8*)(h1 + kc * 32);
#pragma unroll
        for (int t = 0; t < 4; ++t) {
            short8 bfrag = Bs[kc * 256 + t * 64 + frag];
            acc[0][t] = __builtin_amdgcn_mfma_f32_16x16x32_bf16(af0, bfrag, acc[0][t], 0, 0, 0);
            acc[1][t] = __builtin_amdgcn_mfma_f32_16x16x32_bf16(af1, bfrag, acc[1][t], 0, 0, 0);
        }
    }

#pragma unroll
    for (int m = 0; m < 2; ++m) {
        const int rbase = row0 + m * 64 + wv * 16 + quad * 4;
#pragma unroll
        for (int r = 0; r < 4; ++r) {
            int row = rbase + r;
            if (row < N_NODES) {
                float scv = rsqrtf((float)(deg[row] + 1));
#pragma unroll
                for (int t = 0; t < 4; ++t)
                    outb[(size_t)row * 64 + t * 16 + lrow] = f2fp8(scv * acc[m][t][r]);
            }
        }
    }
}

// ---------------- agg2 + mean-pool: F=64 pre-scaled fp8 in, 4 nodes/wave, LDS-combined atomics ----------------
__global__ __launch_bounds__(256) void agg2_pool_kernel(const unsigned int* __restrict__ xw, // [N][16]
                                                        const int* __restrict__ csr_src,
                                                        const int* __restrict__ row_beg,
                                                        const int* __restrict__ row_end,
                                                        const float* __restrict__ bias,
                                                        const int* __restrict__ batch,
                                                        float* __restrict__ gsum,
                                                        float* __restrict__ gcnt) {
    __shared__ float part[16][64];
    __shared__ int bsh[16];
    const int wave = threadIdx.x >> 6;
    const int lane = threadIdx.x & 63;
    const int q = lane >> 4;
    const int c = lane & 15;
    const int nl = wave * 4 + q;
    const int node = blockIdx.x * 16 + nl;

    const int beg = row_beg[node], end = row_end[node];
    const float dvn = rsqrtf((float)(end - beg + 1));

    unsigned int sv = xw[(size_t)node * 16 + c];
    f32x2 slo = __builtin_amdgcn_cvt_pk_f32_fp8(sv, false);
    f32x2 shi = __builtin_amdgcn_cvt_pk_f32_fp8(sv, true);
    float a0 = slo[0], a1 = slo[1], a2 = shi[0], a3 = shi[1];

    for (int e = beg; e < end; e += 16) {
        int s[16];
        s[0] = csr_src[e];
#pragma unroll
        for (int i = 1; i < 16; ++i)
            s[i] = (e + i < end) ? csr_src[e + i] : s[0];
        unsigned int v[16];
#pragma unroll
        for (int i = 0; i < 16; ++i)
            v[i] = xw[(size_t)s[i] * 16 + c];
#pragma unroll
        for (int i = 0; i < 16; ++i) {
            if (i == 0 || e + i < end) {
                f32x2 lo = __builtin_amdgcn_cvt_pk_f32_fp8(v[i], false);
                f32x2 hi = __builtin_amdgcn_cvt_pk_f32_fp8(v[i], true);
                a0 += lo[0]; a1 += lo[1];
                a2 += hi[0]; a3 += hi[1];
            }
        }
    }
    float4 bv = *(const float4*)&bias[c * 4];
    float4 val = make_float4(a0 * dvn + bv.x, a1 * dvn + bv.y,
                             a2 * dvn + bv.z, a3 * dvn + bv.w);
    *(float4*)&part[nl][c * 4] = val;
    if (lane == (q << 4)) bsh[nl] = batch[node];
    __syncthreads();

    if (wave == 0) {
        int b0 = bsh[0];
        bool same = true;
#pragma unroll
        for (int i = 1; i < 16; ++i) same = same && (bsh[i] == b0);
        if (same) {
            float s = 0.f;
#pragma unroll
            for (int i = 0; i < 16; ++i) s += part[i][lane];
            atomicAdd(&gsum[b0 * 64 + lane], s);
            if (lane == 0) atomicAdd(&gcnt[b0], 16.0f);
        } else {
#pragma unroll
            for (int i = 0; i < 16; ++i)
                atomicAdd(&gsum[bsh[i] * 64 + lane], part[i][lane]);
            if (lane == 0) {
#pragma unroll
                for (int i = 0; i < 16; ++i) atomicAdd(&gcnt[bsh[i]], 1.0f);
            }
        }
    }
}

// ---------------- head: mean -> fc -> log_softmax ----------------
__global__ void head_kernel(const float* __restrict__ gsum, const float* __restrict__ gcnt,
                            const float* __restrict__ fcW, const float* __restrict__ fcb,
                            float* __restrict__ out) {
    int g = blockIdx.x * blockDim.x + threadIdx.x;
    if (g >= NUM_GRAPHS) return;
    float c = gcnt[g];
    c = c > 1.f ? c : 1.f;
    float inv = 1.f / c;
    float logits[4];
#pragma unroll
    for (int j = 0; j < 4; ++j) logits[j] = fcb[j];
    for (int k = 0; k < 64; ++k) {
        float m = gsum[g * 64 + k] * inv;
#pragma unroll
        for (int j = 0; j < 4; ++j) logits[j] += m * fcW[k * 4 + j];
    }
    float mx = logits[0];
#pragma unroll
    for (int j = 1; j < 4; ++j) mx = logits[j] > mx ? logits[j] : mx;
    float s = 0.f;
#pragma unroll
    for (int j = 0; j < 4; ++j) s += expf(logits[j] - mx);
    float lse = mx + logf(s);
#pragma unroll
    for (int j = 0; j < 4; ++j) out[g * 4 + j] = logits[j] - lse;
}

extern "C" void kernel_launch(void* const* d_in, const int* in_sizes, int n_in,
                              void* d_out, int out_size, void* d_ws, size_t ws_size,
                              hipStream_t stream) {
    const float* x     = (const float*)d_in[0];
    const int*   ei    = (const int*)d_in[1];     // [2, E]
    const int*   batch = (const int*)d_in[2];
    const float* W1    = (const float*)d_in[3];
    const float* b1    = (const float*)d_in[4];
    const float* W2    = (const float*)d_in[5];
    const float* b2    = (const float*)d_in[6];
    const float* fcW   = (const float*)d_in[7];
    const float* fcb   = (const float*)d_in[8];
    float* out = (float*)d_out;

    const int* src = ei;
    const int* dst = ei + N_EDGES;

    size_t o = 0;
    char* wsb = (char*)d_ws;
    auto take = [&](size_t bytes) -> void* {
        void* p = wsb + o;
        o += (bytes + 255) & ~(size_t)255;
        return p;
    };
    int*   deg       = (int*)take((size_t)N_NODES * 4);
    int*   row_beg   = (int*)take((size_t)N_NODES * 4);
    int*   row_end   = (int*)take((size_t)N_NODES * 4);
    int*   bcursor   = (int*)take((size_t)NBUCKETS * 4);
    int*   csr_src   = (int*)take((size_t)NBUCKETS * CAP * 4);   // bucket-capacity layout
    int*   pairs     = (int*)take((size_t)NBUCKETS * CAP * 4);   // packed (s<<8|d&255)
    ushort* W1t      = (ushort*)take((size_t)128 * 256 * 2);
    ushort* W2t      = (ushort*)take((size_t)64 * 128 * 2);
    unsigned char* bufA = (unsigned char*)take((size_t)N_NODES * 128); // fp8 xw1/xw2 (pre-scaled)
    ushort* bufB     = (ushort*)take((size_t)N_NODES * 128 * 2);       // h1 (bf16)
    float* gsum      = (float*)take((size_t)NUM_GRAPHS * 64 * 4);
    float* gcnt      = (float*)take((size_t)NUM_GRAPHS * 4);
    (void)ws_size;

    const int TB = 256;

    hipMemsetAsync(deg, 0, (size_t)N_NODES * 4, stream);

    setup_kernel<<<SETUP_BLOCKS, TB, 0, stream>>>(bcursor, W1, W1t, W2, W2t, gsum, gcnt,
                                                  dst, deg);

    gemm1_fill_kernel<<<FUSED_BLOCKS, TB, 0, stream>>>(x, W1t, deg, bufA, src, dst,
                                                       bcursor, pairs);

    csr_fill_local_kernel<<<NBUCKETS, TB, 0, stream>>>(pairs, bcursor, csr_src,
                                                       row_beg, row_end);

    agg1_kernel<<<N_NODES / 8, TB, 0, stream>>>((const unsigned int*)bufA, csr_src,
                                                row_beg, row_end, b1, bufB);

    gemm2_kernel<<<(N_NODES + 127) / 128, TB, 0, stream>>>(bufB, W2t, deg, bufA);

    agg2_pool_kernel<<<N_NODES / 16, TB, 0, stream>>>((const unsigned int*)bufA, csr_src,
                                                      row_beg, row_end, b2, batch,
                                                      gsum, gcnt);

    head_kernel<<<(NUM_GRAPHS + TB - 1) / TB, TB, 0, stream>>>(gsum, gcnt, fcW, fcb, out);
}

// Round 4
// 334.800 us; speedup vs baseline: 1.1153x; 1.1153x over previous
//
#include <hip/hip_runtime.h>
#include <hip/hip_bf16.h>

#define N_NODES 100000
#define N_EDGES 1600000
#define NUM_GRAPHS 1000

#define NODES_PER_BUCKET 256
#define BUCKET_SHIFT 8
#define NBUCKETS 391              // ceil(100000/256)
#define CAP 5120                  // bucket capacity: mean 4096 + 16 sigma (deterministic input)

#define G1_BLOCKS 782             // ceil(100000/128)
#define BIN_BLOCKS 781
#define FILL_CHUNK 2052           // divisible by 4; 781*2052 >= 1.6M

typedef __attribute__((ext_vector_type(8))) short short8;
typedef __attribute__((ext_vector_type(4))) float f32x4;
typedef __attribute__((ext_vector_type(2))) float f32x2;
typedef unsigned short ushort;

__device__ __forceinline__ ushort f2bf(float f) {
    unsigned int u = __float_as_uint(f);
    u = u + 0x7fffu + ((u >> 16) & 1u);      // round-to-nearest-even
    return (ushort)(u >> 16);
}

// fp8 e4m3 (OCP on gfx950) encode via HW converter
__device__ __forceinline__ unsigned char f2fp8(float f) {
    return (unsigned char)(__builtin_amdgcn_cvt_pk_fp8_f32(f, f, 0, false) & 0xff);
}

// ---------------- setup: bcursor bases, W1^T bf16, W2^T bf16, zero gsum/gcnt ----------------
__global__ void setup_kernel(int* __restrict__ bcursor,
                             const float* __restrict__ W1, ushort* __restrict__ W1t,
                             const float* __restrict__ W2, ushort* __restrict__ W2t,
                             float* __restrict__ gsum, float* __restrict__ gcnt) {
    int b = blockIdx.x, tid = threadIdx.x;
    if (b < 2) {
        int i = b * 256 + tid;
        if (i < NBUCKETS) bcursor[i] = i * CAP;
    } else if (b < 130) {
        int idx = (b - 2) * 256 + tid;               // 32768
        int n = idx & 127, k = idx >> 7;
        W1t[n * 256 + k] = f2bf(W1[k * 128 + n]);
    } else if (b < 162) {
        int idx = (b - 130) * 256 + tid;             // 8192
        int n = idx & 63, k = idx >> 6;
        W2t[n * 128 + k] = f2bf(W2[k * 64 + n]);
    } else {
        int idx = (b - 162) * 256 + tid;
        if (idx < NUM_GRAPHS * 64) gsum[idx] = 0.f;
        else if (idx < NUM_GRAPHS * 64 + NUM_GRAPHS) gcnt[idx - NUM_GRAPHS * 64] = 0.f;
    }
}
#define SETUP_BLOCKS 416

// ---------------- bin: pack (src<<8 | dst&255) into fixed-capacity dst-buckets ----------------
__global__ __launch_bounds__(256) void bin_kernel(const int* __restrict__ esrc,
                                                  const int* __restrict__ edst,
                                                  int* __restrict__ bcursor,
                                                  int* __restrict__ pairs) {
    __shared__ int scnt[NBUCKETS];
    __shared__ int spos[NBUCKETS];
    const int b = blockIdx.x;
    const int tid = threadIdx.x;
    const int beg = b * FILL_CHUNK;
    int end = beg + FILL_CHUNK;
    if (end > N_EDGES) end = N_EDGES;
    if (beg >= end) return;
    for (int i = tid; i < NBUCKETS; i += 256) scnt[i] = 0;
    __syncthreads();
    for (int e = beg + tid * 4; e < end; e += 1024) {
        int4 d4 = *(const int4*)&edst[e];
        atomicAdd(&scnt[d4.x >> BUCKET_SHIFT], 1);
        atomicAdd(&scnt[d4.y >> BUCKET_SHIFT], 1);
        atomicAdd(&scnt[d4.z >> BUCKET_SHIFT], 1);
        atomicAdd(&scnt[d4.w >> BUCKET_SHIFT], 1);
    }
    __syncthreads();
    for (int i = tid; i < NBUCKETS; i += 256) {
        int c = scnt[i];
        spos[i] = c > 0 ? atomicAdd(&bcursor[i], c) : 0;
    }
    __syncthreads();
    for (int e = beg + tid * 4; e < end; e += 1024) {
        int4 d4 = *(const int4*)&edst[e];
        int4 s4 = *(const int4*)&esrc[e];
        int p0 = atomicAdd(&spos[d4.x >> BUCKET_SHIFT], 1);
        pairs[p0] = (s4.x << 8) | (d4.x & 255);
        int p1 = atomicAdd(&spos[d4.y >> BUCKET_SHIFT], 1);
        pairs[p1] = (s4.y << 8) | (d4.y & 255);
        int p2 = atomicAdd(&spos[d4.z >> BUCKET_SHIFT], 1);
        pairs[p2] = (s4.z << 8) | (d4.z & 255);
        int p3 = atomicAdd(&spos[d4.w >> BUCKET_SHIFT], 1);
        pairs[p3] = (s4.w << 8) | (d4.w & 255);
    }
}

// ---------------- GEMM1: 128 rows/block; A direct from global, B broadcast via LDS ----------------
__global__ __launch_bounds__(256) void gemm1_kernel(const float* __restrict__ x,
                                                    const ushort* __restrict__ W1t,
                                                    unsigned char* __restrict__ outb) {
    // 32 KB: B fragments for half the K range, layout [kcl(4)][t(8)][lrow(16)][quad(4)] x 16B
    __shared__ short8 Bs[2048];
    const int tid = threadIdx.x;
    const int row0 = blockIdx.x * 128;
    const int wv = tid >> 6;
    const int l = tid & 63;
    const int lrow = l & 15;
    const int quad = l >> 4;

    int r0 = row0 + wv * 16 + lrow;          // m=0 rows
    int r1 = r0 + 64;                        // m=1 rows
    if (r0 > N_NODES - 1) r0 = N_NODES - 1;
    if (r1 > N_NODES - 1) r1 = N_NODES - 1;
    const float* xr0 = x + (size_t)r0 * 256 + quad * 8;
    const float* xr1 = x + (size_t)r1 * 256 + quad * 8;
    const int frag = lrow * 4 + quad;        // fragment slot within a (kc,t) tile

    f32x4 acc[2][8];
#pragma unroll
    for (int m = 0; m < 2; ++m)
#pragma unroll
        for (int t = 0; t < 8; ++t) acc[m][t] = (f32x4){0.f, 0.f, 0.f, 0.f};

    for (int s = 0; s < 2; ++s) {
        if (s) __syncthreads();              // all waves done reading stage 0
        // stage 32 KB of W1t into fragment-ordered LDS: 8 x 16B per thread
#pragma unroll
        for (int j = 0; j < 8; ++j) {
            int slot = j * 256 + tid;
            int kcl = slot >> 9, t = (slot >> 6) & 7, lr = (slot >> 2) & 15, q = slot & 3;
            Bs[slot] = *(const short8*)(W1t + (t * 16 + lr) * 256 + (s * 4 + kcl) * 32 + q * 8);
        }
        __syncthreads();

#pragma unroll
        for (int kcl = 0; kcl < 4; ++kcl) {
            const int kc = s * 4 + kcl;
            float4 a00 = *(const float4*)(xr0 + kc * 32);
            float4 a01 = *(const float4*)(xr0 + kc * 32 + 4);
            float4 a10 = *(const float4*)(xr1 + kc * 32);
            float4 a11 = *(const float4*)(xr1 + kc * 32 + 4);
            short8 af0, af1;
            af0[0] = (short)f2bf(a00.x); af0[1] = (short)f2bf(a00.y);
            af0[2] = (short)f2bf(a00.z); af0[3] = (short)f2bf(a00.w);
            af0[4] = (short)f2bf(a01.x); af0[5] = (short)f2bf(a01.y);
            af0[6] = (short)f2bf(a01.z); af0[7] = (short)f2bf(a01.w);
            af1[0] = (short)f2bf(a10.x); af1[1] = (short)f2bf(a10.y);
            af1[2] = (short)f2bf(a10.z); af1[3] = (short)f2bf(a10.w);
            af1[4] = (short)f2bf(a11.x); af1[5] = (short)f2bf(a11.y);
            af1[6] = (short)f2bf(a11.z); af1[7] = (short)f2bf(a11.w);
#pragma unroll
            for (int t = 0; t < 8; ++t) {
                short8 bfrag = Bs[kcl * 512 + t * 64 + frag];
                acc[0][t] = __builtin_amdgcn_mfma_f32_16x16x32_bf16(af0, bfrag, acc[0][t], 0, 0, 0);
                acc[1][t] = __builtin_amdgcn_mfma_f32_16x16x32_bf16(af1, bfrag, acc[1][t], 0, 0, 0);
            }
        }
    }

    // epilogue (unscaled, fp8): C/D layout col=lane&15, row=quad*4+reg
#pragma unroll
    for (int m = 0; m < 2; ++m) {
        const int rbase = row0 + m * 64 + wv * 16 + quad * 4;
#pragma unroll
        for (int t = 0; t < 8; ++t) {
#pragma unroll
            for (int r = 0; r < 4; ++r) {
                int row = rbase + r;
                if (row < N_NODES)
                    outb[(size_t)row * 128 + t * 16 + lrow] = f2fp8(acc[m][t][r]);
            }
        }
    }
}

// ---------------- per-bucket CSR build: histogram + scan + scatter + row/dinv ----------------
__global__ __launch_bounds__(256) void csr_fill_local_kernel(const int* __restrict__ pairs,
                                                             const int* __restrict__ bcursor,
                                                             int* __restrict__ csr_src,
                                                             int* __restrict__ row_beg,
                                                             int* __restrict__ row_end,
                                                             float* __restrict__ dinv) {
    __shared__ int plds[CAP];        // 20 KB
    __shared__ int hist[256];
    __shared__ int scanv[256];
    __shared__ int cur[256];
    const int b = blockIdx.x;
    const int base = b * CAP;
    const int tid = threadIdx.x;
    const int cnt_b = bcursor[b] - base;

    for (int i = tid; i < cnt_b; i += 256) plds[i] = pairs[base + i];
    hist[tid] = 0;
    __syncthreads();
    for (int i = tid; i < cnt_b; i += 256) atomicAdd(&hist[plds[i] & 255], 1);
    __syncthreads();

    int deg = hist[tid];
    scanv[tid] = deg;
    for (int off = 1; off < 256; off <<= 1) {
        __syncthreads();
        int add = (tid >= off) ? scanv[tid - off] : 0;
        __syncthreads();
        scanv[tid] += add;
    }
    __syncthreads();
    int excl = scanv[tid] - deg;

    int node = b * NODES_PER_BUCKET + tid;
    if (node < N_NODES) {
        int beg = base + excl;
        row_beg[node] = beg;
        row_end[node] = beg + deg;
        dinv[node] = rsqrtf((float)(deg + 1));
    }
    cur[tid] = excl;
    __syncthreads();

    for (int i = tid; i < cnt_b; i += 256) {
        int pr = plds[i];
        int pos = base + atomicAdd(&cur[pr & 255], 1);
        csr_src[pos] = ((unsigned int)pr) >> 8;
    }
}

// ---------------- agg1: h(bf16) = relu(dvn*(sum ds*xw_s + dvn*xw_v) + b1); F=128 fp8 in ----------------
__global__ __launch_bounds__(256) void agg1_kernel(const unsigned int* __restrict__ xw,  // [N][32] fp8x4
                                                   const int* __restrict__ csr_src,
                                                   const int* __restrict__ row_beg,
                                                   const int* __restrict__ row_end,
                                                   const float* __restrict__ dinv,
                                                   const float* __restrict__ bias,
                                                   ushort* __restrict__ h) {      // bf16 [N][128]
    const int wave = threadIdx.x >> 6;
    const int lane = threadIdx.x & 63;
    const int h2 = lane >> 5;
    const int c = lane & 31;
    const int node = blockIdx.x * 8 + wave * 2 + h2;

    const int beg = row_beg[node], end = row_end[node];
    const float dvn = rsqrtf((float)(end - beg + 1));

    unsigned int sv = xw[(size_t)node * 32 + c];
    f32x2 slo = __builtin_amdgcn_cvt_pk_f32_fp8(sv, false);
    f32x2 shi = __builtin_amdgcn_cvt_pk_f32_fp8(sv, true);
    float a0 = dvn * slo[0], a1 = dvn * slo[1], a2 = dvn * shi[0], a3 = dvn * shi[1];

    for (int e = beg; e < end; e += 16) {
        int s[16];
        s[0] = csr_src[e];
#pragma unroll
        for (int i = 1; i < 16; ++i)
            s[i] = (e + i < end) ? csr_src[e + i] : s[0];
        unsigned int v[16];
        float ds[16];
#pragma unroll
        for (int i = 0; i < 16; ++i) {
            v[i] = xw[(size_t)s[i] * 32 + c];
            ds[i] = dinv[s[i]];
        }
#pragma unroll
        for (int i = 0; i < 16; ++i) {
            if (i == 0 || e + i < end) {
                f32x2 lo = __builtin_amdgcn_cvt_pk_f32_fp8(v[i], false);
                f32x2 hi = __builtin_amdgcn_cvt_pk_f32_fp8(v[i], true);
                a0 += ds[i] * lo[0]; a1 += ds[i] * lo[1];
                a2 += ds[i] * hi[0]; a3 += ds[i] * hi[1];
            }
        }
    }
    float4 bv = *(const float4*)&bias[c * 4];
    float v0 = a0 * dvn + bv.x, v1 = a1 * dvn + bv.y;
    float v2 = a2 * dvn + bv.z, v3 = a3 * dvn + bv.w;
    ushort4 o;
    o.x = f2bf(v0 > 0.f ? v0 : 0.f);
    o.y = f2bf(v1 > 0.f ? v1 : 0.f);
    o.z = f2bf(v2 > 0.f ? v2 : 0.f);
    o.w = f2bf(v3 > 0.f ? v3 : 0.f);
    *(ushort4*)&h[(size_t)node * 128 + c * 4] = o;
}

// ---------------- GEMM2 (LDS-broadcast B, barrier-free inner loop): outb = fp8(h @ W2) ----------------
__global__ __launch_bounds__(256) void gemm2_kernel(const ushort* __restrict__ h,
                                                    const ushort* __restrict__ W2t,
                                                    unsigned char* __restrict__ outb) {
    // 16 KB: full W2t in fragment order [kc(4)][t(4)][lrow(16)][quad(4)] x 16B
    __shared__ short8 Bs[1024];
    const int tid = threadIdx.x;
    const int row0 = blockIdx.x * 128;
    const int wv = tid >> 6;
    const int l = tid & 63;
    const int lrow = l & 15;
    const int quad = l >> 4;

    int r0 = row0 + wv * 16 + lrow;
    int r1 = r0 + 64;
    if (r0 > N_NODES - 1) r0 = N_NODES - 1;
    if (r1 > N_NODES - 1) r1 = N_NODES - 1;
    const ushort* h0 = h + (size_t)r0 * 128 + quad * 8;
    const ushort* h1 = h + (size_t)r1 * 128 + quad * 8;
    const int frag = lrow * 4 + quad;

#pragma unroll
    for (int j = 0; j < 4; ++j) {
        int slot = j * 256 + tid;
        int kc = slot >> 8, t = (slot >> 6) & 3, lr = (slot >> 2) & 15, q = slot & 3;
        Bs[slot] = *(const short8*)(W2t + (t * 16 + lr) * 128 + kc * 32 + q * 8);
    }
    __syncthreads();

    f32x4 acc[2][4];
#pragma unroll
    for (int m = 0; m < 2; ++m)
#pragma unroll
        for (int t = 0; t < 4; ++t) acc[m][t] = (f32x4){0.f, 0.f, 0.f, 0.f};

#pragma unroll
    for (int kc = 0; kc < 4; ++kc) {
        short8 af0 = *(const short8*)(h0 + kc * 32);
        short8 af1 = *(const short8*)(h1 + kc * 32);
#pragma unroll
        for (int t = 0; t < 4; ++t) {
            short8 bfrag = Bs[kc * 256 + t * 64 + frag];
            acc[0][t] = __builtin_amdgcn_mfma_f32_16x16x32_bf16(af0, bfrag, acc[0][t], 0, 0, 0);
            acc[1][t] = __builtin_amdgcn_mfma_f32_16x16x32_bf16(af1, bfrag, acc[1][t], 0, 0, 0);
        }
    }

#pragma unroll
    for (int m = 0; m < 2; ++m) {
        const int rbase = row0 + m * 64 + wv * 16 + quad * 4;
#pragma unroll
        for (int r = 0; r < 4; ++r) {
            int row = rbase + r;
            if (row < N_NODES) {
#pragma unroll
                for (int t = 0; t < 4; ++t)
                    outb[(size_t)row * 64 + t * 16 + lrow] = f2fp8(acc[m][t][r]);
            }
        }
    }
}

// ---------------- agg2 + mean-pool: F=64 fp8 in, 4 nodes/wave, LDS-combined atomics ----------------
__global__ __launch_bounds__(256) void agg2_pool_kernel(const unsigned int* __restrict__ xw, // [N][16]
                                                        const int* __restrict__ csr_src,
                                                        const int* __restrict__ row_beg,
                                                        const int* __restrict__ row_end,
                                                        const float* __restrict__ dinv,
                                                        const float* __restrict__ bias,
                                                        const int* __restrict__ batch,
                                                        float* __restrict__ gsum,
                                                        float* __restrict__ gcnt) {
    __shared__ float part[16][64];
    __shared__ int bsh[16];
    const int wave = threadIdx.x >> 6;
    const int lane = threadIdx.x & 63;
    const int q = lane >> 4;
    const int c = lane & 15;
    const int nl = wave * 4 + q;
    const int node = blockIdx.x * 16 + nl;

    const int beg = row_beg[node], end = row_end[node];
    const float dvn = rsqrtf((float)(end - beg + 1));

    unsigned int sv = xw[(size_t)node * 16 + c];
    f32x2 slo = __builtin_amdgcn_cvt_pk_f32_fp8(sv, false);
    f32x2 shi = __builtin_amdgcn_cvt_pk_f32_fp8(sv, true);
    float a0 = dvn * slo[0], a1 = dvn * slo[1], a2 = dvn * shi[0], a3 = dvn * shi[1];

    for (int e = beg; e < end; e += 16) {
        int s[16];
        s[0] = csr_src[e];
#pragma unroll
        for (int i = 1; i < 16; ++i)
            s[i] = (e + i < end) ? csr_src[e + i] : s[0];
        unsigned int v[16];
        float ds[16];
#pragma unroll
        for (int i = 0; i < 16; ++i) {
            v[i] = xw[(size_t)s[i] * 16 + c];
            ds[i] = dinv[s[i]];
        }
#pragma unroll
        for (int i = 0; i < 16; ++i) {
            if (i == 0 || e + i < end) {
                f32x2 lo = __builtin_amdgcn_cvt_pk_f32_fp8(v[i], false);
                f32x2 hi = __builtin_amdgcn_cvt_pk_f32_fp8(v[i], true);
                a0 += ds[i] * lo[0]; a1 += ds[i] * lo[1];
                a2 += ds[i] * hi[0]; a3 += ds[i] * hi[1];
            }
        }
    }
    float4 bv = *(const float4*)&bias[c * 4];
    float4 val = make_float4(a0 * dvn + bv.x, a1 * dvn + bv.y,
                             a2 * dvn + bv.z, a3 * dvn + bv.w);
    *(float4*)&part[nl][c * 4] = val;
    if (lane == (q << 4)) bsh[nl] = batch[node];
    __syncthreads();

    if (wave == 0) {
        int b0 = bsh[0];
        bool same = true;
#pragma unroll
        for (int i = 1; i < 16; ++i) same = same && (bsh[i] == b0);
        if (same) {
            float s = 0.f;
#pragma unroll
            for (int i = 0; i < 16; ++i) s += part[i][lane];
            atomicAdd(&gsum[b0 * 64 + lane], s);
            if (lane == 0) atomicAdd(&gcnt[b0], 16.0f);
        } else {
#pragma unroll
            for (int i = 0; i < 16; ++i)
                atomicAdd(&gsum[bsh[i] * 64 + lane], part[i][lane]);
            if (lane == 0) {
#pragma unroll
                for (int i = 0; i < 16; ++i) atomicAdd(&gcnt[bsh[i]], 1.0f);
            }
        }
    }
}

// ---------------- head: mean -> fc -> log_softmax ----------------
__global__ void head_kernel(const float* __restrict__ gsum, const float* __restrict__ gcnt,
                            const float* __restrict__ fcW, const float* __restrict__ fcb,
                            float* __restrict__ out) {
    int g = blockIdx.x * blockDim.x + threadIdx.x;
    if (g >= NUM_GRAPHS) return;
    float c = gcnt[g];
    c = c > 1.f ? c : 1.f;
    float inv = 1.f / c;
    float logits[4];
#pragma unroll
    for (int j = 0; j < 4; ++j) logits[j] = fcb[j];
    for (int k = 0; k < 64; ++k) {
        float m = gsum[g * 64 + k] * inv;
#pragma unroll
        for (int j = 0; j < 4; ++j) logits[j] += m * fcW[k * 4 + j];
    }
    float mx = logits[0];
#pragma unroll
    for (int j = 1; j < 4; ++j) mx = logits[j] > mx ? logits[j] : mx;
    float s = 0.f;
#pragma unroll
    for (int j = 0; j < 4; ++j) s += expf(logits[j] - mx);
    float lse = mx + logf(s);
#pragma unroll
    for (int j = 0; j < 4; ++j) out[g * 4 + j] = logits[j] - lse;
}

extern "C" void kernel_launch(void* const* d_in, const int* in_sizes, int n_in,
                              void* d_out, int out_size, void* d_ws, size_t ws_size,
                              hipStream_t stream) {
    const float* x     = (const float*)d_in[0];
    const int*   ei    = (const int*)d_in[1];     // [2, E]
    const int*   batch = (const int*)d_in[2];
    const float* W1    = (const float*)d_in[3];
    const float* b1    = (const float*)d_in[4];
    const float* W2    = (const float*)d_in[5];
    const float* b2    = (const float*)d_in[6];
    const float* fcW   = (const float*)d_in[7];
    const float* fcb   = (const float*)d_in[8];
    float* out = (float*)d_out;

    const int* src = ei;
    const int* dst = ei + N_EDGES;

    size_t o = 0;
    char* wsb = (char*)d_ws;
    auto take = [&](size_t bytes) -> void* {
        void* p = wsb + o;
        o += (bytes + 255) & ~(size_t)255;
        return p;
    };
    float* dinv      = (float*)take((size_t)N_NODES * 4);
    int*   row_beg   = (int*)take((size_t)N_NODES * 4);
    int*   row_end   = (int*)take((size_t)N_NODES * 4);
    int*   bcursor   = (int*)take((size_t)NBUCKETS * 4);
    int*   csr_src   = (int*)take((size_t)NBUCKETS * CAP * 4);   // bucket-capacity layout
    int*   pairs     = (int*)take((size_t)NBUCKETS * CAP * 4);   // packed (s<<8|d&255)
    ushort* W1t      = (ushort*)take((size_t)128 * 256 * 2);
    ushort* W2t      = (ushort*)take((size_t)64 * 128 * 2);
    unsigned char* bufA = (unsigned char*)take((size_t)N_NODES * 128); // fp8 xw1/xw2
    ushort* bufB     = (ushort*)take((size_t)N_NODES * 128 * 2);       // h1 (bf16)
    float* gsum      = (float*)take((size_t)NUM_GRAPHS * 64 * 4);
    float* gcnt     = (float*)take((size_t)NUM_GRAPHS * 4);
    (void)ws_size;

    const int TB = 256;

    setup_kernel<<<SETUP_BLOCKS, TB, 0, stream>>>(bcursor, W1, W1t, W2, W2t, gsum, gcnt);

    bin_kernel<<<BIN_BLOCKS, TB, 0, stream>>>(src, dst, bcursor, pairs);

    csr_fill_local_kernel<<<NBUCKETS, TB, 0, stream>>>(pairs, bcursor, csr_src,
                                                       row_beg, row_end, dinv);

    gemm1_kernel<<<G1_BLOCKS, TB, 0, stream>>>(x, W1t, bufA);

    agg1_kernel<<<N_NODES / 8, TB, 0, stream>>>((const unsigned int*)bufA, csr_src,
                                                row_beg, row_end, dinv, b1, bufB);

    gemm2_kernel<<<(N_NODES + 127) / 128, TB, 0, stream>>>(bufB, W2t, bufA);

    agg2_pool_kernel<<<N_NODES / 16, TB, 0, stream>>>((const unsigned int*)bufA, csr_src,
                                                      row_beg, row_end, dinv, b2, batch,
                                                      gsum, gcnt);

    head_kernel<<<(NUM_GRAPHS + TB - 1) / TB, TB, 0, stream>>>(gsum, gcnt, fcW, fcb, out);
}

// Round 5
// 306.011 us; speedup vs baseline: 1.2203x; 1.0941x over previous
//
#include <hip/hip_runtime.h>
#include <hip/hip_bf16.h>

#define N_NODES 100000
#define N_EDGES 1600000
#define NUM_GRAPHS 1000

#define NODES_PER_BUCKET 256
#define BUCKET_SHIFT 8
#define NBUCKETS 391              // ceil(100000/256)
#define CAP 5120                  // bucket capacity: mean 4096 + 16 sigma (deterministic input)

#define G1_BLOCKS 1563            // ceil(100000/64)
#define FUSED_BLOCKS 2345         // b%3==2 -> bin (781), else gemm (1564, last guarded)
#define FILL_CHUNK 2052           // divisible by 4; 781*2052 >= 1.6M

typedef __attribute__((ext_vector_type(8))) short short8;
typedef __attribute__((ext_vector_type(4))) float f32x4;
typedef __attribute__((ext_vector_type(2))) float f32x2;
typedef unsigned short ushort;

__device__ __forceinline__ ushort f2bf(float f) {
    unsigned int u = __float_as_uint(f);
    u = u + 0x7fffu + ((u >> 16) & 1u);      // round-to-nearest-even
    return (ushort)(u >> 16);
}

// fp8 e4m3 (OCP on gfx950) encode via HW converter
__device__ __forceinline__ unsigned char f2fp8(float f) {
    return (unsigned char)(__builtin_amdgcn_cvt_pk_fp8_f32(f, f, 0, false) & 0xff);
}

// ---------------- setup: bcursor bases, W1^T bf16, W2^T bf16, zero gsum/gcnt ----------------
__global__ void setup_kernel(int* __restrict__ bcursor,
                             const float* __restrict__ W1, ushort* __restrict__ W1t,
                             const float* __restrict__ W2, ushort* __restrict__ W2t,
                             float* __restrict__ gsum, float* __restrict__ gcnt) {
    int b = blockIdx.x, tid = threadIdx.x;
    if (b < 2) {
        int i = b * 256 + tid;
        if (i < NBUCKETS) bcursor[i] = i * CAP;
    } else if (b < 130) {
        int idx = (b - 2) * 256 + tid;               // 32768
        int n = idx & 127, k = idx >> 7;
        W1t[n * 256 + k] = f2bf(W1[k * 128 + n]);
    } else if (b < 162) {
        int idx = (b - 130) * 256 + tid;             // 8192
        int n = idx & 63, k = idx >> 6;
        W2t[n * 128 + k] = f2bf(W2[k * 64 + n]);
    } else {
        int idx = (b - 162) * 256 + tid;
        if (idx < NUM_GRAPHS * 64) gsum[idx] = 0.f;
        else if (idx < NUM_GRAPHS * 64 + NUM_GRAPHS) gcnt[idx - NUM_GRAPHS * 64] = 0.f;
    }
}
#define SETUP_BLOCKS 416

// ---------------- fused: GEMM1 (64 rows/block, LDS-broadcast B) + edge binning ----------------
__global__ __launch_bounds__(256) void gemm1_fill_kernel(const float* __restrict__ x,
                                                         const ushort* __restrict__ W1t,
                                                         unsigned char* __restrict__ outb,
                                                         const int* __restrict__ esrc,
                                                         const int* __restrict__ edst,
                                                         int* __restrict__ bcursor,
                                                         int* __restrict__ pairs) {
    // 32 KB: B fragments for half the K range, layout [kcl(4)][t(8)][lrow(16)][quad(4)] x 16B
    __shared__ short8 Bs[2048];
    const int b = blockIdx.x;
    const int tid = threadIdx.x;

    if (b % 3 == 2) {
        // ---- bin role: pack (src<<8 | dst&255) into fixed-capacity dst-buckets ----
        int* scnt = (int*)Bs;
        int* spos = scnt + NBUCKETS;
        const int fid = b / 3;
        const int beg = fid * FILL_CHUNK;
        int end = beg + FILL_CHUNK;
        if (end > N_EDGES) end = N_EDGES;
        if (beg >= end) return;
        for (int i = tid; i < NBUCKETS; i += 256) scnt[i] = 0;
        __syncthreads();
        for (int e = beg + tid * 4; e < end; e += 1024) {
            int4 d4 = *(const int4*)&edst[e];
            atomicAdd(&scnt[d4.x >> BUCKET_SHIFT], 1);
            atomicAdd(&scnt[d4.y >> BUCKET_SHIFT], 1);
            atomicAdd(&scnt[d4.z >> BUCKET_SHIFT], 1);
            atomicAdd(&scnt[d4.w >> BUCKET_SHIFT], 1);
        }
        __syncthreads();
        for (int i = tid; i < NBUCKETS; i += 256) {
            int c = scnt[i];
            spos[i] = c > 0 ? atomicAdd(&bcursor[i], c) : 0;
        }
        __syncthreads();
        for (int e = beg + tid * 4; e < end; e += 1024) {
            int4 d4 = *(const int4*)&edst[e];
            int4 s4 = *(const int4*)&esrc[e];
            int p0 = atomicAdd(&spos[d4.x >> BUCKET_SHIFT], 1);
            pairs[p0] = (s4.x << 8) | (d4.x & 255);
            int p1 = atomicAdd(&spos[d4.y >> BUCKET_SHIFT], 1);
            pairs[p1] = (s4.y << 8) | (d4.y & 255);
            int p2 = atomicAdd(&spos[d4.z >> BUCKET_SHIFT], 1);
            pairs[p2] = (s4.z << 8) | (d4.z & 255);
            int p3 = atomicAdd(&spos[d4.w >> BUCKET_SHIFT], 1);
            pairs[p3] = (s4.w << 8) | (d4.w & 255);
        }
        return;
    }

    // ---- GEMM role: 64 rows/block (smaller acc -> higher occupancy); B broadcast via LDS ----
    const int gid = b - (b + 1) / 3;
    if (gid >= G1_BLOCKS) return;
    const int row0 = gid * 64;
    const int wv = tid >> 6;
    const int l = tid & 63;
    const int lrow = l & 15;
    const int quad = l >> 4;

    int r0 = row0 + wv * 16 + lrow;
    if (r0 > N_NODES - 1) r0 = N_NODES - 1;
    const float* xr0 = x + (size_t)r0 * 256 + quad * 8;
    const int frag = lrow * 4 + quad;        // fragment slot within a (kc,t) tile

    f32x4 acc[8];
#pragma unroll
    for (int t = 0; t < 8; ++t) acc[t] = (f32x4){0.f, 0.f, 0.f, 0.f};

    for (int s = 0; s < 2; ++s) {
        if (s) __syncthreads();              // all waves done reading stage 0
        // stage 32 KB of W1t into fragment-ordered LDS: 8 x 16B per thread
#pragma unroll
        for (int j = 0; j < 8; ++j) {
            int slot = j * 256 + tid;
            int kcl = slot >> 9, t = (slot >> 6) & 7, lr = (slot >> 2) & 15, q = slot & 3;
            Bs[slot] = *(const short8*)(W1t + (t * 16 + lr) * 256 + (s * 4 + kcl) * 32 + q * 8);
        }
        __syncthreads();

#pragma unroll
        for (int kcl = 0; kcl < 4; ++kcl) {
            const int kc = s * 4 + kcl;
            float4 a00 = *(const float4*)(xr0 + kc * 32);
            float4 a01 = *(const float4*)(xr0 + kc * 32 + 4);
            short8 af0;
            af0[0] = (short)f2bf(a00.x); af0[1] = (short)f2bf(a00.y);
            af0[2] = (short)f2bf(a00.z); af0[3] = (short)f2bf(a00.w);
            af0[4] = (short)f2bf(a01.x); af0[5] = (short)f2bf(a01.y);
            af0[6] = (short)f2bf(a01.z); af0[7] = (short)f2bf(a01.w);
#pragma unroll
            for (int t = 0; t < 8; ++t) {
                short8 bfrag = Bs[kcl * 512 + t * 64 + frag];
                acc[t] = __builtin_amdgcn_mfma_f32_16x16x32_bf16(af0, bfrag, acc[t], 0, 0, 0);
            }
        }
    }

    // epilogue (unscaled, fp8): C/D layout col=lane&15, row=quad*4+reg
    const int rbase = row0 + wv * 16 + quad * 4;
#pragma unroll
    for (int t = 0; t < 8; ++t) {
#pragma unroll
        for (int r = 0; r < 4; ++r) {
            int row = rbase + r;
            if (row < N_NODES)
                outb[(size_t)row * 128 + t * 16 + lrow] = f2fp8(acc[t][r]);
        }
    }
}

// ---------------- per-bucket CSR build: histogram + scan + scatter + row/dinv ----------------
__global__ __launch_bounds__(256) void csr_fill_local_kernel(const int* __restrict__ pairs,
                                                             const int* __restrict__ bcursor,
                                                             int* __restrict__ csr_src,
                                                             int* __restrict__ row_beg,
                                                             int* __restrict__ row_end,
                                                             float* __restrict__ dinv) {
    __shared__ int plds[CAP];        // 20 KB
    __shared__ int hist[256];
    __shared__ int scanv[256];
    __shared__ int cur[256];
    const int b = blockIdx.x;
    const int base = b * CAP;
    const int tid = threadIdx.x;
    const int cnt_b = bcursor[b] - base;

    for (int i = tid; i < cnt_b; i += 256) plds[i] = pairs[base + i];
    hist[tid] = 0;
    __syncthreads();
    for (int i = tid; i < cnt_b; i += 256) atomicAdd(&hist[plds[i] & 255], 1);
    __syncthreads();

    int deg = hist[tid];
    scanv[tid] = deg;
    for (int off = 1; off < 256; off <<= 1) {
        __syncthreads();
        int add = (tid >= off) ? scanv[tid - off] : 0;
        __syncthreads();
        scanv[tid] += add;
    }
    __syncthreads();
    int excl = scanv[tid] - deg;

    int node = b * NODES_PER_BUCKET + tid;
    if (node < N_NODES) {
        int beg = base + excl;
        row_beg[node] = beg;
        row_end[node] = beg + deg;
        dinv[node] = rsqrtf((float)(deg + 1));
    }
    cur[tid] = excl;
    __syncthreads();

    for (int i = tid; i < cnt_b; i += 256) {
        int pr = plds[i];
        int pos = base + atomicAdd(&cur[pr & 255], 1);
        csr_src[pos] = ((unsigned int)pr) >> 8;
    }
}

// ---------------- agg1: h(bf16) = relu(dvn*(sum ds*xw_s + dvn*xw_v) + b1); F=128 fp8 in ----------------
__global__ __launch_bounds__(256) void agg1_kernel(const unsigned int* __restrict__ xw,  // [N][32] fp8x4
                                                   const int* __restrict__ csr_src,
                                                   const int* __restrict__ row_beg,
                                                   const int* __restrict__ row_end,
                                                   const float* __restrict__ dinv,
                                                   const float* __restrict__ bias,
                                                   ushort* __restrict__ h) {      // bf16 [N][128]
    const int wave = threadIdx.x >> 6;
    const int lane = threadIdx.x & 63;
    const int h2 = lane >> 5;
    const int c = lane & 31;
    const int node = blockIdx.x * 8 + wave * 2 + h2;

    const int beg = row_beg[node], end = row_end[node];
    const float dvn = rsqrtf((float)(end - beg + 1));

    unsigned int sv = xw[(size_t)node * 32 + c];
    f32x2 slo = __builtin_amdgcn_cvt_pk_f32_fp8(sv, false);
    f32x2 shi = __builtin_amdgcn_cvt_pk_f32_fp8(sv, true);
    float a0 = dvn * slo[0], a1 = dvn * slo[1], a2 = dvn * shi[0], a3 = dvn * shi[1];

    for (int e = beg; e < end; e += 16) {
        int s[16];
        s[0] = csr_src[e];
#pragma unroll
        for (int i = 1; i < 16; ++i)
            s[i] = (e + i < end) ? csr_src[e + i] : s[0];
        unsigned int v[16];
        float ds[16];
#pragma unroll
        for (int i = 0; i < 16; ++i) {
            v[i] = xw[(size_t)s[i] * 32 + c];
            ds[i] = dinv[s[i]];
        }
#pragma unroll
        for (int i = 0; i < 16; ++i) {
            if (i == 0 || e + i < end) {
                f32x2 lo = __builtin_amdgcn_cvt_pk_f32_fp8(v[i], false);
                f32x2 hi = __builtin_amdgcn_cvt_pk_f32_fp8(v[i], true);
                a0 += ds[i] * lo[0]; a1 += ds[i] * lo[1];
                a2 += ds[i] * hi[0]; a3 += ds[i] * hi[1];
            }
        }
    }
    float4 bv = *(const float4*)&bias[c * 4];
    float v0 = a0 * dvn + bv.x, v1 = a1 * dvn + bv.y;
    float v2 = a2 * dvn + bv.z, v3 = a3 * dvn + bv.w;
    ushort4 o;
    o.x = f2bf(v0 > 0.f ? v0 : 0.f);
    o.y = f2bf(v1 > 0.f ? v1 : 0.f);
    o.z = f2bf(v2 > 0.f ? v2 : 0.f);
    o.w = f2bf(v3 > 0.f ? v3 : 0.f);
    *(ushort4*)&h[(size_t)node * 128 + c * 4] = o;
}

// ---------------- GEMM2 (LDS-broadcast B, barrier-free inner loop): outb = fp8(h @ W2) ----------------
__global__ __launch_bounds__(256) void gemm2_kernel(const ushort* __restrict__ h,
                                                    const ushort* __restrict__ W2t,
                                                    unsigned char* __restrict__ outb) {
    // 16 KB: full W2t in fragment order [kc(4)][t(4)][lrow(16)][quad(4)] x 16B
    __shared__ short8 Bs[1024];
    const int tid = threadIdx.x;
    const int row0 = blockIdx.x * 128;
    const int wv = tid >> 6;
    const int l = tid & 63;
    const int lrow = l & 15;
    const int quad = l >> 4;

    int r0 = row0 + wv * 16 + lrow;
    int r1 = r0 + 64;
    if (r0 > N_NODES - 1) r0 = N_NODES - 1;
    if (r1 > N_NODES - 1) r1 = N_NODES - 1;
    const ushort* h0 = h + (size_t)r0 * 128 + quad * 8;
    const ushort* h1 = h + (size_t)r1 * 128 + quad * 8;
    const int frag = lrow * 4 + quad;

#pragma unroll
    for (int j = 0; j < 4; ++j) {
        int slot = j * 256 + tid;
        int kc = slot >> 8, t = (slot >> 6) & 3, lr = (slot >> 2) & 15, q = slot & 3;
        Bs[slot] = *(const short8*)(W2t + (t * 16 + lr) * 128 + kc * 32 + q * 8);
    }
    __syncthreads();

    f32x4 acc[2][4];
#pragma unroll
    for (int m = 0; m < 2; ++m)
#pragma unroll
        for (int t = 0; t < 4; ++t) acc[m][t] = (f32x4){0.f, 0.f, 0.f, 0.f};

#pragma unroll
    for (int kc = 0; kc < 4; ++kc) {
        short8 af0 = *(const short8*)(h0 + kc * 32);
        short8 af1 = *(const short8*)(h1 + kc * 32);
#pragma unroll
        for (int t = 0; t < 4; ++t) {
            short8 bfrag = Bs[kc * 256 + t * 64 + frag];
            acc[0][t] = __builtin_amdgcn_mfma_f32_16x16x32_bf16(af0, bfrag, acc[0][t], 0, 0, 0);
            acc[1][t] = __builtin_amdgcn_mfma_f32_16x16x32_bf16(af1, bfrag, acc[1][t], 0, 0, 0);
        }
    }

#pragma unroll
    for (int m = 0; m < 2; ++m) {
        const int rbase = row0 + m * 64 + wv * 16 + quad * 4;
#pragma unroll
        for (int r = 0; r < 4; ++r) {
            int row = rbase + r;
            if (row < N_NODES) {
#pragma unroll
                for (int t = 0; t < 4; ++t)
                    outb[(size_t)row * 64 + t * 16 + lrow] = f2fp8(acc[m][t][r]);
            }
        }
    }
}

// ---------------- agg2 + mean-pool: F=64 fp8 in, 4 nodes/wave, LDS-combined atomics ----------------
__global__ __launch_bounds__(256) void agg2_pool_kernel(const unsigned int* __restrict__ xw, // [N][16]
                                                        const int* __restrict__ csr_src,
                                                        const int* __restrict__ row_beg,
                                                        const int* __restrict__ row_end,
                                                        const float* __restrict__ dinv,
                                                        const float* __restrict__ bias,
                                                        const int* __restrict__ batch,
                                                        float* __restrict__ gsum,
                                                        float* __restrict__ gcnt) {
    __shared__ float part[16][64];
    __shared__ int bsh[16];
    const int wave = threadIdx.x >> 6;
    const int lane = threadIdx.x & 63;
    const int q = lane >> 4;
    const int c = lane & 15;
    const int nl = wave * 4 + q;
    const int node = blockIdx.x * 16 + nl;

    const int beg = row_beg[node], end = row_end[node];
    const float dvn = rsqrtf((float)(end - beg + 1));

    unsigned int sv = xw[(size_t)node * 16 + c];
    f32x2 slo = __builtin_amdgcn_cvt_pk_f32_fp8(sv, false);
    f32x2 shi = __builtin_amdgcn_cvt_pk_f32_fp8(sv, true);
    float a0 = dvn * slo[0], a1 = dvn * slo[1], a2 = dvn * shi[0], a3 = dvn * shi[1];

    for (int e = beg; e < end; e += 16) {
        int s[16];
        s[0] = csr_src[e];
#pragma unroll
        for (int i = 1; i < 16; ++i)
            s[i] = (e + i < end) ? csr_src[e + i] : s[0];
        unsigned int v[16];
        float ds[16];
#pragma unroll
        for (int i = 0; i < 16; ++i) {
            v[i] = xw[(size_t)s[i] * 16 + c];
            ds[i] = dinv[s[i]];
        }
#pragma unroll
        for (int i = 0; i < 16; ++i) {
            if (i == 0 || e + i < end) {
                f32x2 lo = __builtin_amdgcn_cvt_pk_f32_fp8(v[i], false);
                f32x2 hi = __builtin_amdgcn_cvt_pk_f32_fp8(v[i], true);
                a0 += ds[i] * lo[0]; a1 += ds[i] * lo[1];
                a2 += ds[i] * hi[0]; a3 += ds[i] * hi[1];
            }
        }
    }
    float4 bv = *(const float4*)&bias[c * 4];
    float4 val = make_float4(a0 * dvn + bv.x, a1 * dvn + bv.y,
                             a2 * dvn + bv.z, a3 * dvn + bv.w);
    *(float4*)&part[nl][c * 4] = val;
    if (lane == (q << 4)) bsh[nl] = batch[node];
    __syncthreads();

    if (wave == 0) {
        int b0 = bsh[0];
        bool same = true;
#pragma unroll
        for (int i = 1; i < 16; ++i) same = same && (bsh[i] == b0);
        if (same) {
            float s = 0.f;
#pragma unroll
            for (int i = 0; i < 16; ++i) s += part[i][lane];
            atomicAdd(&gsum[b0 * 64 + lane], s);
            if (lane == 0) atomicAdd(&gcnt[b0], 16.0f);
        } else {
#pragma unroll
            for (int i = 0; i < 16; ++i)
                atomicAdd(&gsum[bsh[i] * 64 + lane], part[i][lane]);
            if (lane == 0) {
#pragma unroll
                for (int i = 0; i < 16; ++i) atomicAdd(&gcnt[bsh[i]], 1.0f);
            }
        }
    }
}

// ---------------- head: mean -> fc -> log_softmax ----------------
__global__ void head_kernel(const float* __restrict__ gsum, const float* __restrict__ gcnt,
                            const float* __restrict__ fcW, const float* __restrict__ fcb,
                            float* __restrict__ out) {
    int g = blockIdx.x * blockDim.x + threadIdx.x;
    if (g >= NUM_GRAPHS) return;
    float c = gcnt[g];
    c = c > 1.f ? c : 1.f;
    float inv = 1.f / c;
    float logits[4];
#pragma unroll
    for (int j = 0; j < 4; ++j) logits[j] = fcb[j];
    for (int k = 0; k < 64; ++k) {
        float m = gsum[g * 64 + k] * inv;
#pragma unroll
        for (int j = 0; j < 4; ++j) logits[j] += m * fcW[k * 4 + j];
    }
    float mx = logits[0];
#pragma unroll
    for (int j = 1; j < 4; ++j) mx = logits[j] > mx ? logits[j] : mx;
    float s = 0.f;
#pragma unroll
    for (int j = 0; j < 4; ++j) s += expf(logits[j] - mx);
    float lse = mx + logf(s);
#pragma unroll
    for (int j = 0; j < 4; ++j) out[g * 4 + j] = logits[j] - lse;
}

extern "C" void kernel_launch(void* const* d_in, const int* in_sizes, int n_in,
                              void* d_out, int out_size, void* d_ws, size_t ws_size,
                              hipStream_t stream) {
    const float* x     = (const float*)d_in[0];
    const int*   ei    = (const int*)d_in[1];     // [2, E]
    const int*   batch = (const int*)d_in[2];
    const float* W1    = (const float*)d_in[3];
    const float* b1    = (const float*)d_in[4];
    const float* W2    = (const float*)d_in[5];
    const float* b2    = (const float*)d_in[6];
    const float* fcW   = (const float*)d_in[7];
    const float* fcb   = (const float*)d_in[8];
    float* out = (float*)d_out;

    const int* src = ei;
    const int* dst = ei + N_EDGES;

    size_t o = 0;
    char* wsb = (char*)d_ws;
    auto take = [&](size_t bytes) -> void* {
        void* p = wsb + o;
        o += (bytes + 255) & ~(size_t)255;
        return p;
    };
    float* dinv      = (float*)take((size_t)N_NODES * 4);
    int*   row_beg   = (int*)take((size_t)N_NODES * 4);
    int*   row_end   = (int*)take((size_t)N_NODES * 4);
    int*   bcursor   = (int*)take((size_t)NBUCKETS * 4);
    int*   csr_src   = (int*)take((size_t)NBUCKETS * CAP * 4);   // bucket-capacity layout
    int*   pairs     = (int*)take((size_t)NBUCKETS * CAP * 4);   // packed (s<<8|d&255)
    ushort* W1t      = (ushort*)take((size_t)128 * 256 * 2);
    ushort* W2t      = (ushort*)take((size_t)64 * 128 * 2);
    unsigned char* bufA = (unsigned char*)take((size_t)N_NODES * 128); // fp8 xw1/xw2
    ushort* bufB     = (ushort*)take((size_t)N_NODES * 128 * 2);       // h1 (bf16)
    float* gsum      = (float*)take((size_t)NUM_GRAPHS * 64 * 4);
    float* gcnt      = (float*)take((size_t)NUM_GRAPHS * 4);
    (void)ws_size;

    const int TB = 256;

    setup_kernel<<<SETUP_BLOCKS, TB, 0, stream>>>(bcursor, W1, W1t, W2, W2t, gsum, gcnt);

    gemm1_fill_kernel<<<FUSED_BLOCKS, TB, 0, stream>>>(x, W1t, bufA, src, dst, bcursor, pairs);

    csr_fill_local_kernel<<<NBUCKETS, TB, 0, stream>>>(pairs, bcursor, csr_src,
                                                       row_beg, row_end, dinv);

    agg1_kernel<<<N_NODES / 8, TB, 0, stream>>>((const unsigned int*)bufA, csr_src,
                                                row_beg, row_end, dinv, b1, bufB);

    gemm2_kernel<<<(N_NODES + 127) / 128, TB, 0, stream>>>(bufB, W2t, bufA);

    agg2_pool_kernel<<<N_NODES / 16, TB, 0, stream>>>((const unsigned int*)bufA, csr_src,
                                                      row_beg, row_end, dinv, b2, batch,
                                                      gsum, gcnt);

    head_kernel<<<(NUM_GRAPHS + TB - 1) / TB, TB, 0, stream>>>(gsum, gcnt, fcW, fcb, out);
}